// Round 3
// baseline (22.380 us; speedup 1.0000x reference)
//
#include <hip/hip_runtime.h>

// Problem constants (from reference):
//   x: (PH*PW=49, B=2, C=3, 256, 256) fp32
//   out: (2, 3, 1024, 1024) fp32
//   out[b,c,h,w] = max over patches (i,j) with i*128<=h<i*128+256,
//                  j*128<=w<j*128+256 of x[i*7+j, b, c, h-i*128, w-j*128]
#define PATCH   256
#define STRIDEP 128
#define Bn      2
#define Cn      3
#define Hn      1024
#define Wn      1024
#define PHn     7
#define PWn     7

typedef float v4f __attribute__((ext_vector_type(4)));

__global__ __launch_bounds__(256) void unpatch_max_kernel(
    const float* __restrict__ x, float* __restrict__ out)
{
    // One thread per 8 floats (two float4) of output.
    // Total float8s: 2*3*1024*1024/8 = 786432.
    const int gid = blockIdx.x * blockDim.x + threadIdx.x;
    const int W8  = Wn / 8;                 // 128 float8 per row
    // decompose gid -> (bc, h, w8)
    const int w8   = gid & (W8 - 1);        // W8=128 -> pow2
    const int rest = gid >> 7;
    const int h    = rest & (Hn - 1);       // Hn=1024 -> pow2
    const int bc   = rest >> 10;            // b*Cn + c, in [0,6)
    const int w    = w8 << 3;

    // covering patch rows/cols: {floor(h/128)-1, floor(h/128)} clamped to [0,6].
    // An 8-aligned 8-float span never straddles a 128 boundary, so the j-set
    // is uniform for both float4 halves.
    const int hi = h >> 7;
    const int i1 = hi < PHn ? hi : (PHn - 1);
    const int i0 = hi > 0 ? hi - 1 : 0;
    const int wi = w >> 7;
    const int j1 = wi < PWn ? wi : (PWn - 1);
    const int j0 = wi > 0 ? wi - 1 : 0;

    v4f m0 = (v4f){-INFINITY, -INFINITY, -INFINITY, -INFINITY};
    v4f m1 = m0;

    #pragma unroll 2
    for (int i = i0; i <= i1; ++i) {
        const int ph = h - i * STRIDEP;     // in [0,256)
        #pragma unroll 2
        for (int j = j0; j <= j1; ++j) {
            const int pw  = w - j * STRIDEP;             // in [0,249], 8-aligned
            const int idx = i * PWn + j;                 // patch index
            const size_t off =
                ((size_t)(idx * (Bn * Cn) + bc) * PATCH + ph) * PATCH + pw;
            const v4f v0 = *reinterpret_cast<const v4f*>(x + off);
            const v4f v1 = *reinterpret_cast<const v4f*>(x + off + 4);
            m0 = __builtin_elementwise_max(m0, v0);
            m1 = __builtin_elementwise_max(m1, v1);
        }
    }

    v4f* outp = reinterpret_cast<v4f*>(out + (size_t)gid * 8);
    __builtin_nontemporal_store(m0, outp);
    __builtin_nontemporal_store(m1, outp + 1);
}

extern "C" void kernel_launch(void* const* d_in, const int* in_sizes, int n_in,
                              void* d_out, int out_size, void* d_ws, size_t ws_size,
                              hipStream_t stream)
{
    const float* x = (const float*)d_in[0];
    float* out = (float*)d_out;

    const int total8 = (Bn * Cn * Hn * Wn) / 8;   // 786432
    const int block  = 256;
    const int grid   = total8 / block;            // 3072
    unpatch_max_kernel<<<grid, block, 0, stream>>>(x, out);
}